// Round 3
// baseline (81.867 us; speedup 1.0000x reference)
//
#include <hip/hip_runtime.h>
#include <hip/hip_bf16.h>
#include <stdint.h>

typedef short bf16x8 __attribute__((ext_vector_type(8)));
typedef float f32x4 __attribute__((ext_vector_type(4)));

#define D  512
#define NB 4096
#define NT 8192

__device__ __forceinline__ unsigned short f2bf(float f) {
    __hip_bfloat16 h = __float2bfloat16(f);
    return *reinterpret_cast<unsigned short*>(&h);
}

// Fused fp32->bf16 convert + row squared-norm for BOTH inputs; x rows also
// write the fp32 passthrough (output 0). One wave per row.
__global__ __launch_bounds__(256) void prep_kernel(
    const float* __restrict__ x, const float* __restrict__ y,
    unsigned short* __restrict__ xb, unsigned short* __restrict__ yb,
    float* __restrict__ x2, float* __restrict__ y2, float* __restrict__ copy)
{
    const int grow = blockIdx.x * 4 + (threadIdx.x >> 6);
    const int lane = threadIdx.x & 63;
    const bool isX = grow < NB;
    const int row  = isX ? grow : grow - NB;
    const float* src = isX ? x : y;
    unsigned short* dst = isX ? xb : yb;
    float* norms = isX ? x2 : y2;

    const float4* rp = reinterpret_cast<const float4*>(src + (size_t)row * D);
    float4 v0 = rp[lane * 2];
    float4 v1 = rp[lane * 2 + 1];
    if (isX) {
        float4* cp = reinterpret_cast<float4*>(copy + (size_t)row * D);
        cp[lane * 2]     = v0;
        cp[lane * 2 + 1] = v1;
    }
    float s = v0.x*v0.x + v0.y*v0.y + v0.z*v0.z + v0.w*v0.w
            + v1.x*v1.x + v1.y*v1.y + v1.z*v1.z + v1.w*v1.w;
    union { unsigned short h[8]; int4 v; } u;
    u.h[0] = f2bf(v0.x); u.h[1] = f2bf(v0.y); u.h[2] = f2bf(v0.z); u.h[3] = f2bf(v0.w);
    u.h[4] = f2bf(v1.x); u.h[5] = f2bf(v1.y); u.h[6] = f2bf(v1.z); u.h[7] = f2bf(v1.w);
    reinterpret_cast<int4*>(dst + (size_t)row * D)[lane] = u.v;
    #pragma unroll
    for (int off = 32; off > 0; off >>= 1) s += __shfl_xor(s, off);
    if (lane == 0) norms[row] = s;
}

// 256 persistent blocks (1/CU), each computes TWO col-adjacent 256x256 tiles
// as one unified 16-K-tile 8-phase pipeline (BK=64, 8 waves 2Mx4N,
// counted-vmcnt T3/T4 + T5 setprio). Tile-1's epilogue stores are issued
// mid-pipeline (between j=3 and j=4) and drain under tile-2's compute.
// LDS regions (ushort): REGN(buf, mat, ks) = 2buf x {A,B} x {ks0,ks1},
// each 256x32 bf16 = 16 KiB; total 128 KiB.
#define REGN(b, mat, ks) ((b) * 32768 + (mat) * 16384 + (ks) * 8192)

__global__ __launch_bounds__(512, 2) void gemm_sim_kernel(
    const unsigned short* __restrict__ X, const unsigned short* __restrict__ Y,
    const float* __restrict__ x2, const float* __restrict__ y2,
    float* __restrict__ out)
{
    __shared__ alignas(16) unsigned short lds[65536];   // 128 KiB

    const int tid  = threadIdx.x;
    const int lane = tid & 63;
    const int w    = tid >> 6;
    const int wr   = w >> 2;    // 0..1  (wave row, 128 rows each)
    const int wc   = w & 3;     // 0..3  (wave col, 64 cols each)

    // XCD mapping, L2-fit: XCD covers 8 row-tiles x 8 col-tiles
    // (A panel 2 MB + B panel 2 MB = 4 MB = per-XCD L2).
    const int xcd = blockIdx.x & 7;
    const int idx = blockIdx.x >> 3;          // 0..31
    const int rowTile  = (xcd & 1) * 8 + (idx & 7);    // 0..15
    const int colPair  = (xcd >> 1) * 4 + (idx >> 3);  // 0..15
    const int rowBase  = rowTile * 256;
    const int colBase0 = colPair * 512;
    const int colBase1 = colBase0 + 256;

    // Staging: thread t covers 16 B at LDS offset t*16 (+4096 ushorts for the
    // second 128-row half) of a linear 256x32 half-tile.
    const int rst = tid >> 2;                      // row 0..127
    const int gst = (tid & 3) ^ ((rst >> 1) & 3);  // 16B chunk (lane permute)
    const unsigned short* gA  = X + (size_t)(rowBase  + rst) * D + gst * 8;
    const unsigned short* gB0 = Y + (size_t)(colBase0 + rst) * D + gst * 8;
    const unsigned short* gB1 = Y + (size_t)(colBase1 + rst) * D + gst * 8;
    const int ldst = w * 512;                      // wave-uniform LDS base

    // Read side: chunk permute folds to a per-lane constant.
    const int cread = ((lane >> 4) ^ ((lane >> 1) & 3)) * 8;
    const int aoff = (wr * 128 + (lane & 15)) * 32 + cread;
    const int boff = (wc * 64  + (lane & 15)) * 32 + cread;

    f32x4 acc[8][4] = {};
    bf16x8 bfr[4];

#define STAGE(BUF, MAT, KS, KT) do { \
    const unsigned short* _g = ((MAT) ? (((KT) < 8) ? gB0 : gB1) : gA) \
                               + ((KT) & 7) * 64 + (KS) * 32; \
    const int _l = REGN(BUF, MAT, KS) + ldst; \
    __builtin_amdgcn_global_load_lds((const __attribute__((address_space(1))) void*)_g, \
        (__attribute__((address_space(3))) void*)(lds + _l), 16, 0, 0); \
    __builtin_amdgcn_global_load_lds((const __attribute__((address_space(1))) void*)(_g + 128 * D), \
        (__attribute__((address_space(3))) void*)(lds + _l + 4096), 16, 0, 0); \
} while (0)

#define PHASE(BUF, KS, MH, STG, CKPT) do { \
    bf16x8 _a[4]; \
    if ((MH) == 0) { \
        _Pragma("unroll") \
        for (int n = 0; n < 4; ++n) \
            bfr[n] = *(const bf16x8*)(lds + REGN(BUF, 1, KS) + boff + n * 512); \
    } \
    _Pragma("unroll") \
    for (int m = 0; m < 4; ++m) \
        _a[m] = *(const bf16x8*)(lds + REGN(BUF, 0, KS) + aoff + (MH) * 2048 + m * 512); \
    STG; \
    __builtin_amdgcn_s_barrier(); \
    asm volatile("s_waitcnt lgkmcnt(0)" ::: "memory"); \
    __builtin_amdgcn_s_setprio(1); \
    _Pragma("unroll") \
    for (int m = 0; m < 4; ++m) { \
        _Pragma("unroll") \
        for (int n = 0; n < 4; ++n) \
            acc[(MH) * 4 + m][n] = __builtin_amdgcn_mfma_f32_16x16x32_bf16(_a[m], bfr[n], acc[(MH) * 4 + m][n], 0, 0, 0); \
    } \
    __builtin_amdgcn_s_setprio(0); \
    CKPT; \
    __builtin_amdgcn_s_barrier(); \
} while (0)

#define EPILOGUE(CB) do { \
    const int col0 = (CB) + wc * 64 + (lane & 15); \
    const int row0 = rowBase + wr * 128 + ((lane >> 4) << 2); \
    _Pragma("unroll") \
    for (int mi = 0; mi < 8; ++mi) { \
        const int rbase = row0 + (mi >> 2) * 64 + (mi & 3) * 16; \
        _Pragma("unroll") \
        for (int q = 0; q < 4; ++q) { \
            const int grow = rbase + q; \
            const float xn = x2[grow]; \
            float* orow = out + (size_t)grow * NT; \
            _Pragma("unroll") \
            for (int n = 0; n < 4; ++n) { \
                const int gcol = col0 + n * 16; \
                float sq = fmaxf(xn + y2[gcol] - 2.0f * acc[mi][n][q], 0.0f); \
                orow[gcol] = fminf(rsqrtf(sq), 1.0e6f); \
            } \
        } \
    } \
} while (0)

    // Prologue: K-tile 0 full (buf0), K-tile 1 ks0 (buf1).
    STAGE(0, 0, 0, 0); STAGE(0, 1, 0, 0); STAGE(0, 0, 1, 0); STAGE(0, 1, 1, 0);
    STAGE(1, 0, 0, 1); STAGE(1, 1, 0, 1);
    asm volatile("s_waitcnt vmcnt(4)" ::: "memory");
    __builtin_amdgcn_s_barrier();

    // Unified loop: 16 K-tiles (tile-1 = kt 0..7 vs colBase0, tile-2 = kt 8..15
    // vs colBase1; A panel shared). Stage mapping per iter j (consumes
    // buf0=t2j, buf1=t2j+1): p0/p1 -> (2j+1).ks1, p2..p5 -> (2j+2), p6/p7 ->
    // (2j+3).ks0. Checkpoints vmcnt(4) end of p3/p7; final drain vmcnt(0) at
    // j=7 p3. Tile-1 epilogue slots in after j=3 (stores drain under tile-2).
#pragma unroll
    for (int j = 0; j < 8; ++j) {
        const int t1 = 2 * j + 1, t2 = 2 * j + 2, t3 = 2 * j + 3;
        PHASE(0, 0, 0, STAGE(1, 0, 1, t1), ((void)0));
        PHASE(0, 0, 1, STAGE(1, 1, 1, t1), ((void)0));
        PHASE(0, 1, 0, if (t2 < 16) STAGE(0, 0, 0, t2), ((void)0));
        PHASE(0, 1, 1, if (t2 < 16) STAGE(0, 1, 0, t2),
              if (j < 7) { asm volatile("s_waitcnt vmcnt(4)" ::: "memory"); }
              else       { asm volatile("s_waitcnt vmcnt(0)" ::: "memory"); });
        PHASE(1, 0, 0, if (t2 < 16) STAGE(0, 0, 1, t2), ((void)0));
        PHASE(1, 0, 1, if (t2 < 16) STAGE(0, 1, 1, t2), ((void)0));
        PHASE(1, 1, 0, if (t3 < 16) STAGE(1, 0, 0, t3), ((void)0));
        PHASE(1, 1, 1, if (t3 < 16) STAGE(1, 1, 0, t3),
              if (j < 7) { asm volatile("s_waitcnt vmcnt(4)" ::: "memory"); });
        if (j == 3) {
            EPILOGUE(colBase0);           // tile-1 stores: issue, don't wait
            #pragma unroll
            for (int mi = 0; mi < 8; ++mi)
                #pragma unroll
                for (int n = 0; n < 4; ++n)
                    acc[mi][n] = (f32x4){0.f, 0.f, 0.f, 0.f};
        }
    }
#undef PHASE
#undef STAGE

    EPILOGUE(colBase1);
}

extern "C" void kernel_launch(void* const* d_in, const int* in_sizes, int n_in,
                              void* d_out, int out_size, void* d_ws, size_t ws_size,
                              hipStream_t stream)
{
    const float* x = (const float*)d_in[0];
    const float* y = (const float*)d_in[1];
    float* out = (float*)d_out;
    char* ws = (char*)d_ws;

    unsigned short* xb = (unsigned short*)ws;                 // 4 MB
    unsigned short* yb = (unsigned short*)(ws + (4u << 20));  // 8 MB
    float* x2 = (float*)(ws + (12u << 20));                   // 16 KB
    float* y2 = (float*)(ws + (12u << 20) + 4 * NB);          // 32 KB

    prep_kernel<<<(NB + NT) / 4, 256, 0, stream>>>(x, y, xb, yb, x2, y2, out);
    gemm_sim_kernel<<<256, 512, 0, stream>>>(xb, yb, x2, y2, out + (size_t)NB * D);
}

// Round 4
// 62.110 us; speedup vs baseline: 1.3181x; 1.3181x over previous
//
#include <hip/hip_runtime.h>
#include <hip/hip_bf16.h>
#include <stdint.h>

typedef short bf16x8 __attribute__((ext_vector_type(8)));
typedef float f32x4 __attribute__((ext_vector_type(4)));

#define D  512
#define NB 4096
#define NT 8192

__device__ __forceinline__ unsigned short f2bf(float f) {
    __hip_bfloat16 h = __float2bfloat16(f);
    return *reinterpret_cast<unsigned short*>(&h);
}

// Fused fp32->bf16 convert + row squared-norm for BOTH inputs; x rows also
// write the fp32 passthrough (output 0). One wave per row.
__global__ __launch_bounds__(256) void prep_kernel(
    const float* __restrict__ x, const float* __restrict__ y,
    unsigned short* __restrict__ xb, unsigned short* __restrict__ yb,
    float* __restrict__ x2, float* __restrict__ y2, float* __restrict__ copy)
{
    const int grow = blockIdx.x * 4 + (threadIdx.x >> 6);
    const int lane = threadIdx.x & 63;
    const bool isX = grow < NB;
    const int row  = isX ? grow : grow - NB;
    const float* src = isX ? x : y;
    unsigned short* dst = isX ? xb : yb;
    float* norms = isX ? x2 : y2;

    const float4* rp = reinterpret_cast<const float4*>(src + (size_t)row * D);
    float4 v0 = rp[lane * 2];
    float4 v1 = rp[lane * 2 + 1];
    if (isX) {
        float4* cp = reinterpret_cast<float4*>(copy + (size_t)row * D);
        cp[lane * 2]     = v0;
        cp[lane * 2 + 1] = v1;
    }
    float s = v0.x*v0.x + v0.y*v0.y + v0.z*v0.z + v0.w*v0.w
            + v1.x*v1.x + v1.y*v1.y + v1.z*v1.z + v1.w*v1.w;
    union { unsigned short h[8]; int4 v; } u;
    u.h[0] = f2bf(v0.x); u.h[1] = f2bf(v0.y); u.h[2] = f2bf(v0.z); u.h[3] = f2bf(v0.w);
    u.h[4] = f2bf(v1.x); u.h[5] = f2bf(v1.y); u.h[6] = f2bf(v1.z); u.h[7] = f2bf(v1.w);
    reinterpret_cast<int4*>(dst + (size_t)row * D)[lane] = u.v;
    #pragma unroll
    for (int off = 32; off > 0; off >>= 1) s += __shfl_xor(s, off);
    if (lane == 0) norms[row] = s;
}

// 128x256 tile, BK=32, 4 waves (1Mx4N, wave-tile 128x64), counted-vmcnt
// 4-phase engine over K-tile pairs (buf0=even kt, buf1=odd kt), 48 KiB LDS
// -> 2 blocks/CU co-resident: one block's prologue/epilogue store-drain
// overlaps the other's MFMA (TLP replaces the impossible in-pipeline
// store overlap — vmcnt can't separate loads from stores).
// LDS (ushort): buf b at b*12288: A 128x32 @0 (8 KB), B 256x32 @4096 (16 KB).
__global__ __launch_bounds__(256, 2) void gemm_sim_kernel(
    const unsigned short* __restrict__ X, const unsigned short* __restrict__ Y,
    const float* __restrict__ x2, const float* __restrict__ y2,
    float* __restrict__ out)
{
    __shared__ alignas(16) unsigned short lds[24576];   // 48 KiB

    const int t    = threadIdx.x;
    const int lane = t & 63;
    const int w    = t >> 6;          // 0..3, wave col (64 cols each)

    // XCD swizzle: 1024 blocks, 8 XCDs; each XCD gets 8 rowTiles x 16 colTiles.
    const int bid = blockIdx.x;
    const int xcd = bid & 7;
    const int idx = bid >> 3;                         // 0..127
    const int rowBase = ((xcd & 3) * 8 + (idx & 7)) * 128;
    const int colBase = ((xcd >> 2) * 16 + (idx >> 3)) * 256;

    // Staging: thread t writes 16 B chunks at LDS ushort off t*8 (+L*2048).
    // Chunk-XOR swizzle (rule #21): stored chunk c' holds global chunk
    // c' ^ ((row>>1)&3); folds to the t-only constant below for all L.
    const int swz = ((t & 3) ^ ((t >> 3) & 3)) * 8;
    const unsigned short* gA = X + (size_t)(rowBase + (t >> 2)) * D + swz;
    const unsigned short* gB = Y + (size_t)(colBase + (t >> 2)) * D + swz;

    // Read side: swizzle folds to a per-lane constant.
    const int cread = ((lane >> 4) ^ ((lane >> 1) & 3)) * 8;
    const int aoff = (lane & 15) * 32 + cread;                 // + buf + mh*2048 + m*512
    const int boff = 4096 + (w * 64 + (lane & 15)) * 32 + cread;  // + buf + n*512

    f32x4 acc[8][4] = {};
    bf16x8 bfr[4];

#define STAGE_A(BUF, KT) do { \
    _Pragma("unroll") \
    for (int L = 0; L < 2; ++L) \
        __builtin_amdgcn_global_load_lds( \
            (const __attribute__((address_space(1))) void*)(gA + (size_t)L * 64 * D + (KT) * 32), \
            (__attribute__((address_space(3))) void*)(lds + (BUF) * 12288 + t * 8 + L * 2048), 16, 0, 0); \
} while (0)

#define STAGE_B(BUF, KT) do { \
    _Pragma("unroll") \
    for (int L = 0; L < 4; ++L) \
        __builtin_amdgcn_global_load_lds( \
            (const __attribute__((address_space(1))) void*)(gB + (size_t)L * 64 * D + (KT) * 32), \
            (__attribute__((address_space(3))) void*)(lds + (BUF) * 12288 + 4096 + t * 8 + L * 2048), 16, 0, 0); \
} while (0)

#define PHASE(BUF, MH, STG, CKPT) do { \
    bf16x8 _a[4]; \
    if ((MH) == 0) { \
        _Pragma("unroll") \
        for (int n = 0; n < 4; ++n) \
            bfr[n] = *(const bf16x8*)(lds + (BUF) * 12288 + boff + n * 512); \
    } \
    _Pragma("unroll") \
    for (int m = 0; m < 4; ++m) \
        _a[m] = *(const bf16x8*)(lds + (BUF) * 12288 + aoff + (MH) * 2048 + m * 512); \
    STG; \
    __builtin_amdgcn_s_barrier(); \
    asm volatile("s_waitcnt lgkmcnt(0)" ::: "memory"); \
    __builtin_amdgcn_s_setprio(1); \
    _Pragma("unroll") \
    for (int m = 0; m < 4; ++m) { \
        _Pragma("unroll") \
        for (int n = 0; n < 4; ++n) \
            acc[(MH) * 4 + m][n] = __builtin_amdgcn_mfma_f32_16x16x32_bf16(_a[m], bfr[n], acc[(MH) * 4 + m][n], 0, 0, 0); \
    } \
    __builtin_amdgcn_s_setprio(0); \
    CKPT; \
    __builtin_amdgcn_s_barrier(); \
} while (0)

    // Prologue: B0, A0 (kt0) + B1 (kt1 B-half). vmcnt(4) leaves B1 in flight.
    STAGE_B(0, 0); STAGE_A(0, 0); STAGE_B(1, 1);
    asm volatile("s_waitcnt vmcnt(4)" ::: "memory");
    __builtin_amdgcn_s_barrier();

    // 8 iterations x 2 K-tiles (K=512, BK=32 -> 16 kt).
    // Stage slots: p0: A(2j+1), p1: B(2j+2), p2: A(2j+2), p3: B(2j+3).
    // Checkpoints (after MFMA): p1 vmcnt(4) [j=7: vmcnt(0)], p3 vmcnt(4).
    // Every region write is issued after the closing barrier of its last
    // reader's phase; every read is covered by a checkpoint whose newest-4
    // excludes it (audit in round-4 notes).
#pragma unroll
    for (int j = 0; j < 8; ++j) {
        PHASE(0, 0, STAGE_A(1, 2 * j + 1), ((void)0));
        PHASE(0, 1, if (j < 7) STAGE_B(0, 2 * j + 2),
              if (j < 7) { asm volatile("s_waitcnt vmcnt(4)" ::: "memory"); }
              else       { asm volatile("s_waitcnt vmcnt(0)" ::: "memory"); });
        PHASE(1, 0, if (j < 7) STAGE_A(0, 2 * j + 2), ((void)0));
        PHASE(1, 1, if (j < 7) STAGE_B(1, 2 * j + 3),
              if (j < 7) { asm volatile("s_waitcnt vmcnt(4)" ::: "memory"); });
    }
#undef PHASE
#undef STAGE_A
#undef STAGE_B

    // Epilogue: C/D layout col = lane&15, row = (lane>>4)*4 + reg.
    const int col0 = colBase + w * 64 + (lane & 15);
    const int row0 = rowBase + ((lane >> 4) << 2);
    #pragma unroll
    for (int mi = 0; mi < 8; ++mi) {
        const int rbase = row0 + (mi >> 2) * 64 + (mi & 3) * 16;
        #pragma unroll
        for (int q = 0; q < 4; ++q) {
            const int grow = rbase + q;
            const float xn = x2[grow];
            float* orow = out + (size_t)grow * NT;
            #pragma unroll
            for (int n = 0; n < 4; ++n) {
                const int gcol = col0 + n * 16;
                float sq = fmaxf(xn + y2[gcol] - 2.0f * acc[mi][n][q], 0.0f);
                orow[gcol] = fminf(rsqrtf(sq), 1.0e6f);  // rsqrt(0)=inf -> clipped
            }
        }
    }
}

extern "C" void kernel_launch(void* const* d_in, const int* in_sizes, int n_in,
                              void* d_out, int out_size, void* d_ws, size_t ws_size,
                              hipStream_t stream)
{
    const float* x = (const float*)d_in[0];
    const float* y = (const float*)d_in[1];
    float* out = (float*)d_out;
    char* ws = (char*)d_ws;

    unsigned short* xb = (unsigned short*)ws;                 // 4 MB
    unsigned short* yb = (unsigned short*)(ws + (4u << 20));  // 8 MB
    float* x2 = (float*)(ws + (12u << 20));                   // 16 KB
    float* y2 = (float*)(ws + (12u << 20) + 4 * NB);          // 32 KB

    prep_kernel<<<(NB + NT) / 4, 256, 0, stream>>>(x, y, xb, yb, x2, y2, out);
    gemm_sim_kernel<<<1024, 256, 0, stream>>>(xb, yb, x2, y2, out + (size_t)NB * D);
}

// Round 5
// 60.641 us; speedup vs baseline: 1.3500x; 1.0242x over previous
//
#include <hip/hip_runtime.h>
#include <hip/hip_bf16.h>
#include <stdint.h>

typedef short bf16x8 __attribute__((ext_vector_type(8)));
typedef float f32x4 __attribute__((ext_vector_type(4)));

#define D  512
#define NB 4096
#define NT 8192

__device__ __forceinline__ unsigned short f2bf(float f) {
    __hip_bfloat16 h = __float2bfloat16(f);
    return *reinterpret_cast<unsigned short*>(&h);
}

// Fused fp32->bf16 convert + row squared-norm for BOTH inputs; x rows also
// write the fp32 passthrough (output 0). One wave per row. HBM-floor bound.
__global__ __launch_bounds__(256) void prep_kernel(
    const float* __restrict__ x, const float* __restrict__ y,
    unsigned short* __restrict__ xb, unsigned short* __restrict__ yb,
    float* __restrict__ x2, float* __restrict__ y2, float* __restrict__ copy)
{
    const int grow = blockIdx.x * 4 + (threadIdx.x >> 6);
    const int lane = threadIdx.x & 63;
    const bool isX = grow < NB;
    const int row  = isX ? grow : grow - NB;
    const float* src = isX ? x : y;
    unsigned short* dst = isX ? xb : yb;
    float* norms = isX ? x2 : y2;

    const float4* rp = reinterpret_cast<const float4*>(src + (size_t)row * D);
    float4 v0 = rp[lane * 2];
    float4 v1 = rp[lane * 2 + 1];
    if (isX) {
        float4* cp = reinterpret_cast<float4*>(copy + (size_t)row * D);
        cp[lane * 2]     = v0;
        cp[lane * 2 + 1] = v1;
    }
    float s = v0.x*v0.x + v0.y*v0.y + v0.z*v0.z + v0.w*v0.w
            + v1.x*v1.x + v1.y*v1.y + v1.z*v1.z + v1.w*v1.w;
    union { unsigned short h[8]; int4 v; } u;
    u.h[0] = f2bf(v0.x); u.h[1] = f2bf(v0.y); u.h[2] = f2bf(v0.z); u.h[3] = f2bf(v0.w);
    u.h[4] = f2bf(v1.x); u.h[5] = f2bf(v1.y); u.h[6] = f2bf(v1.z); u.h[7] = f2bf(v1.w);
    reinterpret_cast<int4*>(dst + (size_t)row * D)[lane] = u.v;
    #pragma unroll
    for (int off = 32; off > 0; off >>= 1) s += __shfl_xor(s, off);
    if (lane == 0) norms[row] = s;
}

// 128x256 tile, BK=32, 4 waves (1Mx4N, wave-tile 128x64), counted-vmcnt
// engine with THREE rotating LDS buffers (deep prefetch: kt+1 AND kt+2 in
// flight; one vmcnt(6) checkpoint per K-tile). 72 KiB LDS -> 2 blocks/CU
// co-resident (TLP hides store bursts and phase gaps).
// LDS (ushort): buf b at b*12288: A 128x32 @+0 (8 KB), B 256x32 @+4096 (16 KB).
__global__ __launch_bounds__(256, 2) void gemm_sim_kernel(
    const unsigned short* __restrict__ X, const unsigned short* __restrict__ Y,
    const float* __restrict__ x2, const float* __restrict__ y2,
    float* __restrict__ out)
{
    __shared__ alignas(16) unsigned short lds[36864];   // 72 KiB

    const int t    = threadIdx.x;
    const int lane = t & 63;
    const int w    = t >> 6;          // 0..3, wave col (64 cols each)

    // XCD swizzle, L2-fit: each XCD covers 16 rowTiles x 8 colTiles
    // (A 2 MB + B 2 MB = 4 MB = per-XCD L2).
    const int bid = blockIdx.x;
    const int xcd = bid & 7;
    const int idx = bid >> 3;                          // 0..127
    const int rowBase = ((xcd >> 2) * 16 + (idx & 15)) * 128;
    const int colBase = ((xcd & 3) * 8 + (idx >> 4)) * 256;

    // Staging: thread t writes 16 B chunks at LDS ushort off t*8 (+L*2048).
    // Chunk-XOR swizzle (rule #21): stored chunk c' holds global chunk
    // c' ^ ((row>>1)&3); folds to t-only constants for all L.
    const int swz = ((t & 3) ^ ((t >> 3) & 3)) * 8;
    const unsigned short* gA = X + (size_t)(rowBase + (t >> 2)) * D + swz;
    const unsigned short* gB = Y + (size_t)(colBase + (t >> 2)) * D + swz;

    // Read side: swizzle folds to a per-lane constant.
    const int cread = ((lane >> 4) ^ ((lane >> 1) & 3)) * 8;
    const int aoff = (lane & 15) * 32 + cread;                    // + buf + mh*2048 + m*512
    const int boff = 4096 + (w * 64 + (lane & 15)) * 32 + cread;  // + buf + n*512

    f32x4 acc[8][4] = {};
    bf16x8 bfr[4];

#define STAGE_A(BUF, KT) do { \
    _Pragma("unroll") \
    for (int L = 0; L < 2; ++L) \
        __builtin_amdgcn_global_load_lds( \
            (const __attribute__((address_space(1))) void*)(gA + (size_t)L * 64 * D + (KT) * 32), \
            (__attribute__((address_space(3))) void*)(lds + (BUF) * 12288 + t * 8 + L * 2048), 16, 0, 0); \
} while (0)

#define STAGE_B(BUF, KT) do { \
    _Pragma("unroll") \
    for (int L = 0; L < 4; ++L) \
        __builtin_amdgcn_global_load_lds( \
            (const __attribute__((address_space(1))) void*)(gB + (size_t)L * 64 * D + (KT) * 32), \
            (__attribute__((address_space(3))) void*)(lds + (BUF) * 12288 + 4096 + t * 8 + L * 2048), 16, 0, 0); \
} while (0)

#define PHASE(BUF, MH, STG, CKPT) do { \
    bf16x8 _a[4]; \
    if ((MH) == 0) { \
        _Pragma("unroll") \
        for (int n = 0; n < 4; ++n) \
            bfr[n] = *(const bf16x8*)(lds + (BUF) * 12288 + boff + n * 512); \
    } \
    _Pragma("unroll") \
    for (int m = 0; m < 4; ++m) \
        _a[m] = *(const bf16x8*)(lds + (BUF) * 12288 + aoff + (MH) * 2048 + m * 512); \
    STG; \
    __builtin_amdgcn_s_barrier(); \
    asm volatile("s_waitcnt lgkmcnt(0)" ::: "memory"); \
    __builtin_amdgcn_s_setprio(1); \
    _Pragma("unroll") \
    for (int m = 0; m < 4; ++m) { \
        _Pragma("unroll") \
        for (int n = 0; n < 4; ++n) \
            acc[(MH) * 4 + m][n] = __builtin_amdgcn_mfma_f32_16x16x32_bf16(_a[m], bfr[n], acc[(MH) * 4 + m][n], 0, 0, 0); \
    } \
    __builtin_amdgcn_s_setprio(0); \
    CKPT; \
    __builtin_amdgcn_s_barrier(); \
} while (0)

    // Prologue: kt0 + kt1 staged (12 loads); vmcnt(6) -> kt0 landed.
    STAGE_A(0, 0); STAGE_B(0, 0);
    STAGE_A(1, 1); STAGE_B(1, 1);
    asm volatile("s_waitcnt vmcnt(6)" ::: "memory");
    __builtin_amdgcn_s_barrier();

    // 16 K-tiles, buffer = kt%3. Per kt: mh0 phase stages A(kt+2), mh1 phase
    // stages B(kt+2) then checkpoints vmcnt(6) (retires kt+1's 6 loads,
    // leaves kt+2's 6 in flight). Write-after-read: buf[(kt+2)%3] was last
    // read at kt-1, separated by two barriers. Tail: kt=14 drains vmcnt(0).
#pragma unroll
    for (int kt = 0; kt < 16; ++kt) {
        PHASE((kt % 3), 0,
              if (kt + 2 < 16) STAGE_A(((kt + 2) % 3), kt + 2),
              ((void)0));
        PHASE((kt % 3), 1,
              if (kt + 2 < 16) STAGE_B(((kt + 2) % 3), kt + 2),
              if (kt < 14)      { asm volatile("s_waitcnt vmcnt(6)" ::: "memory"); }
              else if (kt == 14){ asm volatile("s_waitcnt vmcnt(0)" ::: "memory"); });
    }
#undef PHASE
#undef STAGE_A
#undef STAGE_B

    // Epilogue: C/D layout col = lane&15, row = (lane>>4)*4 + reg.
    const int col0 = colBase + w * 64 + (lane & 15);
    const int row0 = rowBase + ((lane >> 4) << 2);
    #pragma unroll
    for (int mi = 0; mi < 8; ++mi) {
        const int rbase = row0 + (mi >> 2) * 64 + (mi & 3) * 16;
        #pragma unroll
        for (int q = 0; q < 4; ++q) {
            const int grow = rbase + q;
            const float xn = x2[grow];
            float* orow = out + (size_t)grow * NT;
            #pragma unroll
            for (int n = 0; n < 4; ++n) {
                const int gcol = col0 + n * 16;
                float sq = fmaxf(xn + y2[gcol] - 2.0f * acc[mi][n][q], 0.0f);
                orow[gcol] = fminf(rsqrtf(sq), 1.0e6f);  // rsqrt(0)=inf -> clipped
            }
        }
    }
}

extern "C" void kernel_launch(void* const* d_in, const int* in_sizes, int n_in,
                              void* d_out, int out_size, void* d_ws, size_t ws_size,
                              hipStream_t stream)
{
    const float* x = (const float*)d_in[0];
    const float* y = (const float*)d_in[1];
    float* out = (float*)d_out;
    char* ws = (char*)d_ws;

    unsigned short* xb = (unsigned short*)ws;                 // 4 MB
    unsigned short* yb = (unsigned short*)(ws + (4u << 20));  // 8 MB
    float* x2 = (float*)(ws + (12u << 20));                   // 16 KB
    float* y2 = (float*)(ws + (12u << 20) + 4 * NB);          // 32 KB

    prep_kernel<<<(NB + NT) / 4, 256, 0, stream>>>(x, y, xb, yb, x2, y2, out);
    gemm_sim_kernel<<<1024, 256, 0, stream>>>(xb, yb, x2, y2, out + (size_t)NB * D);
}